// Round 14
// baseline (214.898 us; speedup 1.0000x reference)
//
#include <hip/hip_runtime.h>
#include <math.h>

#define DIM 1024
#define T_SEQ 2048
#define NBATCH 2
#define HEADS 16
#define HD 64
#define NTOK 4096  // NBATCH * T_SEQ
#define THRESH 0.29514f
#define SHARP 15.0f
#define LOG2E 1.4426950408889634f

typedef __attribute__((ext_vector_type(8))) short bf16x8;
typedef __attribute__((ext_vector_type(4))) float f32x4;
typedef __attribute__((ext_vector_type(4))) unsigned int u32x4;

__device__ __forceinline__ unsigned short f2b(float f) {
    unsigned int u = __float_as_uint(f);
    unsigned int r = (u + 0x7FFFu + ((u >> 16) & 1u)) >> 16;
    return (unsigned short)r;
}
__device__ __forceinline__ float b2f(unsigned short u) {
    return __uint_as_float(((unsigned int)u) << 16);
}
// pack two f32 -> bf16x2 dword (lo in low half), round-half-up (<=0.5 ulp).
__device__ __forceinline__ unsigned int pack2_bf16(float lo, float hi) {
    unsigned int a = __float_as_uint(lo) + 0x8000u;
    unsigned int b = __float_as_uint(hi) + 0x8000u;
    return __builtin_amdgcn_perm(b, a, 0x07060302u);  // {b.b3,b.b2,a.b3,a.b2}
}

__device__ __forceinline__ void async_cp16(const unsigned short* g, unsigned short* l) {
    __builtin_amdgcn_global_load_lds(
        (const __attribute__((address_space(1))) unsigned int*)g,
        (__attribute__((address_space(3))) unsigned int*)l, 16, 0, 0);
}

// ---------------------------------------------------------------------------
// Kernel 1 (fused): blocks [0,1024) = LayerNorm -> bf16 x_norm + bf16 x;
// blocks [1024,2048) = fp32 [K][N] weight -> bf16 transposed [N][K].
// ---------------------------------------------------------------------------
__global__ __launch_bounds__(256) void prep_kernel(
    const float* __restrict__ x, const float* __restrict__ lnw, const float* __restrict__ lnb,
    unsigned short* __restrict__ xnb, unsigned short* __restrict__ xb,
    const float* __restrict__ W0, const float* __restrict__ W1,
    const float* __restrict__ W2, const float* __restrict__ W3,
    unsigned short* __restrict__ T0, unsigned short* __restrict__ T1,
    unsigned short* __restrict__ T2, unsigned short* __restrict__ T3) {
    __shared__ float tile[64][65];
    if (blockIdx.x < 1024) {
        // ---- LayerNorm part ----
        int row = blockIdx.x * 4 + (threadIdx.x >> 6);
        int lane = threadIdx.x & 63;
        const float4* xr = (const float4*)(x + (size_t)row * DIM);
        float4 v[4];
        float s = 0.f, ss = 0.f;
#pragma unroll
        for (int i = 0; i < 4; i++) {
            v[i] = xr[lane + i * 64];
            s += v[i].x + v[i].y + v[i].z + v[i].w;
            ss += v[i].x * v[i].x + v[i].y * v[i].y + v[i].z * v[i].z + v[i].w * v[i].w;
        }
#pragma unroll
        for (int off = 32; off; off >>= 1) {
            s += __shfl_xor(s, off);
            ss += __shfl_xor(ss, off);
        }
        float m = s * (1.f / DIM);
        float rstd = rsqrtf(ss * (1.f / DIM) - m * m + 1e-5f);
#pragma unroll
        for (int i = 0; i < 4; i++) {
            int e = (lane + i * 64) * 4;
            float4 lw = *(const float4*)&lnw[e];
            float4 lb = *(const float4*)&lnb[e];
            ushort4 un, ur;
            un.x = f2b((v[i].x - m) * rstd * lw.x + lb.x);
            un.y = f2b((v[i].y - m) * rstd * lw.y + lb.y);
            un.z = f2b((v[i].z - m) * rstd * lw.z + lb.z);
            un.w = f2b((v[i].w - m) * rstd * lw.w + lb.w);
            ur.x = f2b(v[i].x); ur.y = f2b(v[i].y); ur.z = f2b(v[i].z); ur.w = f2b(v[i].w);
            *(ushort4*)&xnb[(size_t)row * DIM + e] = un;
            *(ushort4*)&xb[(size_t)row * DIM + e] = ur;
        }
    } else {
        // ---- weight transpose part ----
        const int i = blockIdx.x - 1024;
        const int z = i >> 8;
        const int k0 = ((i >> 4) & 15) * 64, n0 = (i & 15) * 64;
        const float* W = (z == 0) ? W0 : (z == 1) ? W1 : (z == 2) ? W2 : W3;
        unsigned short* T = (z == 0) ? T0 : (z == 1) ? T1 : (z == 2) ? T2 : T3;
        const int r = threadIdx.x >> 3;
        const int c = (threadIdx.x & 7) * 8;
#pragma unroll
        for (int half = 0; half < 2; half++) {
            int rr = r + half * 32;
            float4 a = *(const float4*)&W[(size_t)(k0 + rr) * DIM + n0 + c];
            float4 b = *(const float4*)&W[(size_t)(k0 + rr) * DIM + n0 + c + 4];
            tile[rr][c + 0] = a.x; tile[rr][c + 1] = a.y; tile[rr][c + 2] = a.z; tile[rr][c + 3] = a.w;
            tile[rr][c + 4] = b.x; tile[rr][c + 5] = b.y; tile[rr][c + 6] = b.z; tile[rr][c + 7] = b.w;
        }
        __syncthreads();
#pragma unroll
        for (int half = 0; half < 2; half++) {
            int dd = r + half * 32;
            bf16x8 o;
#pragma unroll
            for (int j = 0; j < 8; j++) o[j] = (short)f2b(tile[c + j][dd]);
            *(bf16x8*)&T[(size_t)(n0 + dd) * DIM + k0 + c] = o;
        }
    }
}

// ---------------------------------------------------------------------------
// Kernel 3: bf16 MFMA GEMM, BK=32, 4 waves (2x2), XCD swizzle.
// R14: MODE0 = the missing cell of the {1 vs 2 barriers} x {drain vs
// counted} matrix: ONE s_barrier per k-step AND counted vmcnt. 3 buffers,
// stage only 1 tile ahead — the 3rd buffer exists to break the WAR race
// that otherwise forces a second barrier: stage at iter ks writes
// buf (ks+1)%3 whose last readers were compute(ks-2), and every wave past
// barrier B(ks-1) has completed C(ks-2) (program order). RAW: vmcnt(4)
// retires exactly tile ks (4 newest loads stay in flight), barrier makes
// it collective. LDS 48KB -> 3 blocks/CU preserved.
// MODE 0: tile 128x128, z=0/1 (Q/K): fused l2norm + gate; z=2 (V): plain.
//   z=0 (Q) output pre-scaled by K1 = -SHARP*LOG2E (sigmoid fold); +K0 goes
//   in the attn MFMA C-operand. gq gate uses the UNSCALED normalized q.
// MODE 1: tile 128x64, C = collapse @ Wot^T + bias (R13 structure).
// ---------------------------------------------------------------------------
template <int MODE>
__global__ __launch_bounds__(256) void gemm_mfma_kernel(
    const unsigned short* __restrict__ A0,
    const unsigned short* __restrict__ Bt0, const unsigned short* __restrict__ Bt1,
    const unsigned short* __restrict__ Bt2, const float* __restrict__ bias,
    const float* __restrict__ gq, const float* __restrict__ gk,
    unsigned short* __restrict__ Oq, unsigned short* __restrict__ Ok,
    unsigned short* __restrict__ Ov, float* __restrict__ gq_t, float* __restrict__ gk_t,
    float* __restrict__ Oout, const unsigned short* __restrict__ A2) {
    constexpr int NT = (MODE == 0) ? 4 : 2;    // n-frags per wave; block n-tile = NT*32
    constexpr int NBUF = (MODE == 0) ? 3 : 2;
    __shared__ __align__(16) unsigned short As[NBUF][128 * 32];
    __shared__ __align__(16) unsigned short Bs[NBUF][NT * 32 * 32];
    const int tid = threadIdx.x;
    const int lane = tid & 63, w = tid >> 6;
    const int l16 = lane & 15, quad = lane >> 4;
    const int wm = w >> 1, wn = w & 1;
    int m0, n0, z = 0;
    if constexpr (MODE == 0) {
        // 768 blocks; w = z*256 + m*8 + n; XCD chunk = 96 consecutive w.
        const int f = blockIdx.x + (blockIdx.y << 5) + (blockIdx.z << 8);
        const int ww = (f & 7) * 96 + (f >> 3);
        z = ww >> 8;
        m0 = ((ww >> 3) & 31) * 128;
        n0 = (ww & 7) * 128;
    } else {
        // 512 blocks; w = m*16 + n; XCD chunk = 64 consecutive w (4m x 16n).
        const int f = blockIdx.x + (blockIdx.y << 5);
        const int ww = (f & 7) * 64 + (f >> 3);
        m0 = (ww >> 4) * 128;
        n0 = (ww & 15) * 64;
    }
    const unsigned short* A;
    const unsigned short* Bt;
    if constexpr (MODE == 0) {
        A = (z == 2) ? A2 : A0;
        Bt = (z == 0) ? Bt0 : (z == 1) ? Bt1 : Bt2;
    } else {
        A = A0;
        Bt = Bt0;
    }
    f32x4 acc[4][NT] = {};
    const int kswz = (l16 >> 1) & 3;

    // staging geometry (per thread, 2 instances)
    const int lin0 = tid, lin1 = 256 + tid;
    const int sm0 = lin0 >> 2, sk0 = (lin0 & 3) ^ ((sm0 >> 1) & 3);
    const int sm1 = lin1 >> 2, sk1 = (lin1 & 3) ^ ((sm1 >> 1) & 3);

    auto stage_async = [&](int kb, int k0) {
        async_cp16(Bt + (size_t)(n0 + sm0) * DIM + k0 + sk0 * 8, &Bs[kb][lin0 * 8]);
        if constexpr (MODE == 0)
            async_cp16(Bt + (size_t)(n0 + sm1) * DIM + k0 + sk1 * 8, &Bs[kb][lin1 * 8]);
        async_cp16(A + (size_t)(m0 + sm0) * DIM + k0 + sk0 * 8, &As[kb][lin0 * 8]);
        async_cp16(A + (size_t)(m0 + sm1) * DIM + k0 + sk1 * 8, &As[kb][lin1 * 8]);
    };

    auto compute = [&](int cur) {
        bf16x8 af[4], bfr[NT];
#pragma unroll
        for (int t = 0; t < 4; t++) {
            int ma = wm * 64 + t * 16 + l16;
            af[t] = *(const bf16x8*)(&As[cur][ma * 32 + ((quad ^ kswz) * 8)]);
        }
#pragma unroll
        for (int t = 0; t < NT; t++) {
            int nb = wn * (NT * 16) + t * 16 + l16;
            bfr[t] = *(const bf16x8*)(&Bs[cur][nb * 32 + ((quad ^ kswz) * 8)]);
        }
#pragma unroll
        for (int mt = 0; mt < 4; mt++)
#pragma unroll
            for (int nt = 0; nt < NT; nt++)
                acc[mt][nt] =
                    __builtin_amdgcn_mfma_f32_16x16x32_bf16(af[mt], bfr[nt], acc[mt][nt], 0, 0, 0);
    };

    if constexpr (MODE == 0) {
        // 1-barrier counted-vmcnt pipeline, depth-1 lookahead, 3 buffers.
        stage_async(0, 0);  // tile 0 -> buf 0
        int cur = 0;
        for (int ks = 0; ks < DIM / 32; ks++) {
            if (ks + 1 < DIM / 32) {
                const int nb = (cur == 2) ? 0 : cur + 1;
                stage_async(nb, (ks + 1) * 32);                   // tile ks+1
                asm volatile("s_waitcnt vmcnt(4)" ::: "memory");  // tile ks landed (mine)
            } else {
                asm volatile("s_waitcnt vmcnt(0)" ::: "memory");  // final tile
            }
            __builtin_amdgcn_s_barrier();  // collective: all tile-ks loads landed;
                                           // also fences buf reuse (see header)
            compute(cur);
            cur = (cur == 2) ? 0 : cur + 1;
        }
    } else {
        stage_async(0, 0);
        __syncthreads();
        for (int ks = 0; ks < DIM / 32; ks++) {
            const int cur = ks & 1;
            if (ks + 1 < DIM / 32) stage_async(cur ^ 1, (ks + 1) * 32);
            compute(cur);
            __syncthreads();
        }
    }

    if constexpr (MODE == 0) {
        const int h = (n0 + wn * 64) >> 6;  // this wave's head
        if (z <= 1) {
            constexpr float QSCALE = -SHARP * LOG2E;  // fold sigmoid arg scale into Q
            const float* gvec = (z == 0) ? gq : gk;
            float* gate = (z == 0) ? gq_t : gk_t;
            unsigned short* O = (z == 0) ? Oq : Ok;
            const float oscale = (z == 0) ? QSCALE : 1.0f;
            float gv[4];
#pragma unroll
            for (int nt = 0; nt < 4; nt++) gv[nt] = gvec[nt * 16 + l16];
#pragma unroll
            for (int mt = 0; mt < 4; mt++) {
#pragma unroll
                for (int r = 0; r < 4; r++) {
                    float ss = 0.f;
#pragma unroll
                    for (int nt = 0; nt < 4; nt++) ss += acc[mt][nt][r] * acc[mt][nt][r];
#pragma unroll
                    for (int msk = 1; msk < 16; msk <<= 1) ss += __shfl_xor(ss, msk);
                    float rn = __builtin_amdgcn_rcpf(fmaxf(sqrtf(ss), 1e-12f));
                    float vn[4], gg = 0.f;
#pragma unroll
                    for (int nt = 0; nt < 4; nt++) {
                        vn[nt] = acc[mt][nt][r] * rn;
                        gg += vn[nt] * gv[nt];
                    }
#pragma unroll
                    for (int msk = 1; msk < 16; msk <<= 1) gg += __shfl_xor(gg, msk);
                    int tok = m0 + wm * 64 + mt * 16 + quad * 4 + r;
                    int b = tok >> 11, t = tok & 2047;
                    size_t rowbase = ((size_t)(b * HEADS + h) * T_SEQ + t) * HD;
#pragma unroll
                    for (int nt = 0; nt < 4; nt++)
                        O[rowbase + nt * 16 + l16] = f2b(vn[nt] * oscale);
                    if (l16 == 0) gate[(b * HEADS + h) * T_SEQ + t] = gg;
                }
            }
        } else {
#pragma unroll
            for (int mt = 0; mt < 4; mt++) {
#pragma unroll
                for (int r = 0; r < 4; r++) {
                    int tok = m0 + wm * 64 + mt * 16 + quad * 4 + r;
                    int b = tok >> 11, t = tok & 2047;
                    size_t rowbase = ((size_t)(b * HEADS + h) * T_SEQ + t) * HD;
#pragma unroll
                    for (int nt = 0; nt < 4; nt++)
                        Ov[rowbase + nt * 16 + l16] = f2b(acc[mt][nt][r]);
                }
            }
        }
    } else {
        float bias_r[NT];
#pragma unroll
        for (int nt = 0; nt < NT; nt++) bias_r[nt] = bias[n0 + wn * (NT * 16) + nt * 16 + l16];
#pragma unroll
        for (int mt = 0; mt < 4; mt++) {
#pragma unroll
            for (int r = 0; r < 4; r++) {
                int tok = m0 + wm * 64 + mt * 16 + quad * 4 + r;
#pragma unroll
                for (int nt = 0; nt < NT; nt++) {
                    int n = n0 + wn * (NT * 16) + nt * 16 + l16;
                    Oout[(size_t)tok * DIM + n] = acc[mt][nt][r] + bias_r[nt];
                }
            }
        }
    }
}

// ---------------------------------------------------------------------------
// Kernel 4: bf16 transpose V[bh][t][d] -> Vt[bh][d][t], fused gate_k scale.
// ---------------------------------------------------------------------------
__global__ __launch_bounds__(256) void vtrans_kernel(const unsigned short* __restrict__ Vn,
                                                     const float* __restrict__ gk_t,
                                                     unsigned short* __restrict__ Vt) {
    __shared__ float tile[64][65];
    const int bh = blockIdx.y;
    const int t0 = blockIdx.x * 64;
    const int r = threadIdx.x >> 3;
    const int c = (threadIdx.x & 7) * 8;
    const unsigned short* src = Vn + (size_t)bh * T_SEQ * HD;
#pragma unroll
    for (int half = 0; half < 2; half++) {
        int rr = r + half * 32;
        float gkv = gk_t[bh * T_SEQ + t0 + rr];
        bf16x8 v = *(const bf16x8*)(src + (size_t)(t0 + rr) * HD + c);
#pragma unroll
        for (int j = 0; j < 8; j++) tile[rr][c + j] = b2f((unsigned short)v[j]) * gkv;
    }
    __syncthreads();
    unsigned short* dst = Vt + (size_t)bh * HD * T_SEQ;
#pragma unroll
    for (int half = 0; half < 2; half++) {
        int dd = r + half * 32;
        bf16x8 o;
#pragma unroll
        for (int j = 0; j < 8; j++) o[j] = (short)f2b(tile[c + j][dd]);
        *(bf16x8*)(dst + (size_t)dd * T_SEQ + t0 + c) = o;
    }
}

// ---------------------------------------------------------------------------
// Kernel 5: MFMA gated attention (R13: full s-range per block, 512 blocks,
// final gq-scaled bf16 collapse written directly — verified -8us net).
// ---------------------------------------------------------------------------
__global__ __launch_bounds__(256, 4) void attn_mfma_kernel(
    const unsigned short* __restrict__ Qn, const unsigned short* __restrict__ Kn,
    const unsigned short* __restrict__ Vt, const float* __restrict__ gateq,
    unsigned short* __restrict__ coll) {
    __shared__ __align__(16) unsigned short Ks[2][64 * 64];   // [s][d], swizzled groups
    __shared__ __align__(16) unsigned short VtL[2][64 * 64];  // [d][s], swizzled groups
    const int tid = threadIdx.x;
    const int lane = tid & 63, w = tid >> 6;
    const int quad = lane >> 4, l16 = lane & 15;
    // XCD-clustering remap (bijective over 512 blocks; xcd = flat%8):
    // panel(b,h) = (f&7)*4 + ((f>>3)>>4); t-block = (f>>3)&15.
    const int f = blockIdx.x + 16 * blockIdx.y + 256 * blockIdx.z;
    const int q_ = f >> 3;
    const int panel = (f & 7) * 4 + (q_ >> 4);
    const int t0 = (q_ & 15) * 128;
    const int h = panel & 15;
    const int b = panel >> 4;
    const int bh = b * HEADS + h;
    const size_t base = (size_t)bh * T_SEQ * HD;  // == bh*HD*T_SEQ for Vt
    constexpr float K0 = THRESH * SHARP * LOG2E;  // sigmoid arg = sacc (K1 in Q)
    const f32x4 k0v = {K0, K0, K0, K0};

    // Detect v_permlane16_swap_b32 output order once (uniform).
    int det0 = quad, det1 = quad + 4;
    asm("v_permlane16_swap_b32 %0, %1" : "+v"(det0), "+v"(det1));
    const bool flagA = (__builtin_amdgcn_readfirstlane(det0) == 0);

    // Q (B-operand of QK) fragments: 32 rows/wave, 2 m-tiles, in regs.
    bf16x8 fq[2][2];
#pragma unroll
    for (int mt = 0; mt < 2; mt++) {
        const unsigned short* qrow = Qn + base + (size_t)(t0 + w * 32 + mt * 16 + l16) * HD;
        fq[mt][0] = *(const bf16x8*)(qrow + quad * 8);
        fq[mt][1] = *(const bf16x8*)(qrow + 32 + quad * 8);
    }

    f32x4 oacc[4][2] = {};  // [dt][mt], O^T C-layout
    const int srow = tid >> 3;     // staging row 0..31 (+32 second inst)
    const int sgp = tid & 7;       // physical 16B group
    const int swz = l16 & 7;

    auto stage_chunk = [&](unsigned short* ksn, unsigned short* vtn, int s0) {
#pragma unroll
        for (int half = 0; half < 2; half++) {
            int row = srow + half * 32;
            int g = sgp ^ (row & 7);  // logical group for this physical slot
            async_cp16(Kn + base + (size_t)(s0 + row) * HD + g * 8, ksn + row * 64 + sgp * 8);
            async_cp16(Vt + base + (size_t)row * T_SEQ + s0 + g * 8, vtn + row * 64 + sgp * 8);
        }
    };

    auto do_chunk = [&](const unsigned short* ksb, const unsigned short* vtb) {
#pragma unroll
        for (int kh = 0; kh < 2; kh++) {
            // ---- QK for this kh's s-range (2 ct tiles); sigmoid; bf16 S in regs ----
            unsigned int p[2][2][2];  // [mt][ct2][dword]
#pragma unroll
            for (int ct2 = 0; ct2 < 2; ct2++) {
                const int ct = 2 * kh + ct2;
                const unsigned short* krow = ksb + (ct * 16 + l16) * 64;
                bf16x8 fk0 = *(const bf16x8*)(krow + (quad ^ swz) * 8);
                bf16x8 fk1 = *(const bf16x8*)(krow + ((quad + 4) ^ swz) * 8);
#pragma unroll
                for (int mt = 0; mt < 2; mt++) {
                    __builtin_amdgcn_s_setprio(1);
                    f32x4 s1 =
                        __builtin_amdgcn_mfma_f32_16x16x32_bf16(fk0, fq[mt][0], k0v, 0, 0, 0);
                    f32x4 sacc =
                        __builtin_amdgcn_mfma_f32_16x16x32_bf16(fk1, fq[mt][1], s1, 0, 0, 0);
                    __builtin_amdgcn_s_setprio(0);
                    float w0 = __builtin_amdgcn_rcpf(1.f + __builtin_amdgcn_exp2f(sacc[0]));
                    float w1 = __builtin_amdgcn_rcpf(1.f + __builtin_amdgcn_exp2f(sacc[1]));
                    float w2 = __builtin_amdgcn_rcpf(1.f + __builtin_amdgcn_exp2f(sacc[2]));
                    float w3 = __builtin_amdgcn_rcpf(1.f + __builtin_amdgcn_exp2f(sacc[3]));
                    p[mt][ct2][0] = pack2_bf16(w0, w1);
                    p[mt][ct2][1] = pack2_bf16(w2, w3);
                }
            }
            // ---- SV for this kh: O^T += V^T S^T, B-frag via permlane16_swap ----
            int gv = (4 * kh + 2 * (quad & 1) + (quad >> 1)) ^ swz;
            bf16x8 fv[4];
#pragma unroll
            for (int dt = 0; dt < 4; dt++)
                fv[dt] = *(const bf16x8*)(vtb + (dt * 16 + l16) * 64 + gv * 8);
#pragma unroll
            for (int mt = 0; mt < 2; mt++) {
                unsigned int aL = p[mt][0][0], aH = p[mt][0][1];
                unsigned int bL = p[mt][1][0], bH = p[mt][1][1];
                asm("v_permlane16_swap_b32 %0, %1" : "+v"(aL), "+v"(bL));
                asm("v_permlane16_swap_b32 %0, %1" : "+v"(aH), "+v"(bH));
                u32x4 bt;
                if (flagA) {  // wave-uniform branch, no per-lane selects
                    bt.x = aL; bt.y = aH; bt.z = bL; bt.w = bH;
                } else {
                    bt.x = bL; bt.y = bH; bt.z = aL; bt.w = aH;
                }
                bf16x8 fs = __builtin_bit_cast(bf16x8, bt);
                __builtin_amdgcn_s_setprio(1);
#pragma unroll
                for (int dt = 0; dt < 4; dt++)
                    oacc[dt][mt] =
                        __builtin_amdgcn_mfma_f32_16x16x32_bf16(fv[dt], fs, oacc[dt][mt], 0, 0, 0);
                __builtin_amdgcn_s_setprio(0);
            }
        }
        __syncthreads();
    };

    stage_chunk(&Ks[0][0], &VtL[0][0], 0);
    __syncthreads();

    for (int j = 0; j < T_SEQ / 128; j++) {
        // even chunk (buf 0): prefetch odd chunk into buf 1 (always in range)
        stage_chunk(&Ks[1][0], &VtL[1][0], j * 128 + 64);
        do_chunk(&Ks[0][0], &VtL[0][0]);
        // odd chunk (buf 1): prefetch next even chunk into buf 0
        if (j + 1 < T_SEQ / 128) stage_chunk(&Ks[0][0], &VtL[0][0], j * 128 + 128);
        do_chunk(&Ks[1][0], &VtL[1][0]);
    }

    // ---- epilogue: O^T lanes hold 4 consecutive d; * gate_q, b64 writes ----
#pragma unroll
    for (int mt = 0; mt < 2; mt++) {
        int t = t0 + w * 32 + mt * 16 + l16;
        float gq_v = gateq[bh * T_SEQ + t];
        unsigned short* dst = coll + ((size_t)b * T_SEQ + t) * DIM + h * HD;
#pragma unroll
        for (int dt = 0; dt < 4; dt++) {
            ushort4 o;
            o.x = f2b(oacc[dt][mt][0] * gq_v);
            o.y = f2b(oacc[dt][mt][1] * gq_v);
            o.z = f2b(oacc[dt][mt][2] * gq_v);
            o.w = f2b(oacc[dt][mt][3] * gq_v);
            *(ushort4*)(dst + dt * 16 + quad * 4) = o;
        }
    }
}

// ---------------------------------------------------------------------------
extern "C" void kernel_launch(void* const* d_in, const int* in_sizes, int n_in,
                              void* d_out, int out_size, void* d_ws, size_t ws_size,
                              hipStream_t stream) {
    const float* x = (const float*)d_in[0];
    const float* Wq = (const float*)d_in[1];
    const float* Wk = (const float*)d_in[2];
    const float* Wv = (const float*)d_in[3];
    const float* gq = (const float*)d_in[4];
    const float* gk = (const float*)d_in[5];
    const float* Wo = (const float*)d_in[6];
    const float* bo = (const float*)d_in[7];
    const float* lnw = (const float*)d_in[8];
    const float* lnb = (const float*)d_in[9];
    float* out = (float*)d_out;

    // Workspace ~59.3 MB. Aliases safe by stream ordering: Vt overwrites xnb
    // (dead after QKV GEMM); coll overwrites xb (dead after QKV GEMM).
    unsigned short* ws = (unsigned short*)d_ws;
    unsigned short* xnb = ws;                           // bf16 [4096][1024]
    unsigned short* xb = xnb + (size_t)NTOK * DIM;      // bf16 [4096][1024]
    unsigned short* Wqt = xb + (size_t)NTOK * DIM;      // bf16 [1024][1024] (W^T)
    unsigned short* Wkt = Wqt + (size_t)DIM * DIM;
    unsigned short* Wvt = Wkt + (size_t)DIM * DIM;
    unsigned short* Wot = Wvt + (size_t)DIM * DIM;
    unsigned short* Q16 = Wot + (size_t)DIM * DIM;      // bf16 [B,H,T,hd] (normalized * K1)
    unsigned short* K16 = Q16 + (size_t)NTOK * DIM;     // bf16 (normalized)
    unsigned short* Vn = K16 + (size_t)NTOK * DIM;      // bf16 [B,H,T,hd]
    float* gq_t = (float*)(Vn + (size_t)NTOK * DIM);    // [B,H,T]
    float* gk_t = gq_t + NBATCH * HEADS * T_SEQ;
    unsigned short* Vt = xnb;   // alias: bf16 [B,H,hd,T], gk-scaled
    unsigned short* coll = xb;  // alias: bf16 final collapse [B,T,D]

    prep_kernel<<<2048, 256, 0, stream>>>(x, lnw, lnb, xnb, xb, Wq, Wk, Wv, Wo, Wqt, Wkt, Wvt,
                                          Wot);
    gemm_mfma_kernel<0><<<dim3(NTOK / 128, DIM / 128, 3), 256, 0, stream>>>(
        xnb, Wqt, Wkt, Wvt, nullptr, gq, gk, Q16, K16, Vn, gq_t, gk_t, nullptr, xb);
    vtrans_kernel<<<dim3(T_SEQ / 64, NBATCH * HEADS), 256, 0, stream>>>(Vn, gk_t, Vt);
    attn_mfma_kernel<<<dim3(16, 16, 2), 256, 0, stream>>>(Q16, K16, Vt, gq_t, coll);
    gemm_mfma_kernel<1><<<dim3(NTOK / 128, DIM / 64, 1), 256, 0, stream>>>(
        coll, Wot, nullptr, nullptr, bo, nullptr, nullptr, nullptr, nullptr, nullptr, nullptr,
        nullptr, out, nullptr);
}

// Round 15
// 213.157 us; speedup vs baseline: 1.0082x; 1.0082x over previous
//
#include <hip/hip_runtime.h>
#include <math.h>

#define DIM 1024
#define T_SEQ 2048
#define NBATCH 2
#define HEADS 16
#define HD 64
#define NTOK 4096  // NBATCH * T_SEQ
#define THRESH 0.29514f
#define SHARP 15.0f
#define LOG2E 1.4426950408889634f

typedef __attribute__((ext_vector_type(8))) short bf16x8;
typedef __attribute__((ext_vector_type(4))) float f32x4;
typedef __attribute__((ext_vector_type(4))) unsigned int u32x4;

__device__ __forceinline__ unsigned short f2b(float f) {
    unsigned int u = __float_as_uint(f);
    unsigned int r = (u + 0x7FFFu + ((u >> 16) & 1u)) >> 16;
    return (unsigned short)r;
}
__device__ __forceinline__ float b2f(unsigned short u) {
    return __uint_as_float(((unsigned int)u) << 16);
}
// pack two f32 -> bf16x2 dword (lo in low half), round-half-up (<=0.5 ulp).
__device__ __forceinline__ unsigned int pack2_bf16(float lo, float hi) {
    unsigned int a = __float_as_uint(lo) + 0x8000u;
    unsigned int b = __float_as_uint(hi) + 0x8000u;
    return __builtin_amdgcn_perm(b, a, 0x07060302u);  // {b.b3,b.b2,a.b3,a.b2}
}

__device__ __forceinline__ void async_cp16(const unsigned short* g, unsigned short* l) {
    __builtin_amdgcn_global_load_lds(
        (const __attribute__((address_space(1))) unsigned int*)g,
        (__attribute__((address_space(3))) unsigned int*)l, 16, 0, 0);
}

// ---------------------------------------------------------------------------
// Kernel 1 (fused): blocks [0,1024) = LayerNorm -> bf16 x_norm + bf16 x;
// blocks [1024,2048) = fp32 [K][N] weight -> bf16 transposed [N][K].
// ---------------------------------------------------------------------------
__global__ __launch_bounds__(256) void prep_kernel(
    const float* __restrict__ x, const float* __restrict__ lnw, const float* __restrict__ lnb,
    unsigned short* __restrict__ xnb, unsigned short* __restrict__ xb,
    const float* __restrict__ W0, const float* __restrict__ W1,
    const float* __restrict__ W2, const float* __restrict__ W3,
    unsigned short* __restrict__ T0, unsigned short* __restrict__ T1,
    unsigned short* __restrict__ T2, unsigned short* __restrict__ T3) {
    __shared__ float tile[64][65];
    if (blockIdx.x < 1024) {
        // ---- LayerNorm part ----
        int row = blockIdx.x * 4 + (threadIdx.x >> 6);
        int lane = threadIdx.x & 63;
        const float4* xr = (const float4*)(x + (size_t)row * DIM);
        float4 v[4];
        float s = 0.f, ss = 0.f;
#pragma unroll
        for (int i = 0; i < 4; i++) {
            v[i] = xr[lane + i * 64];
            s += v[i].x + v[i].y + v[i].z + v[i].w;
            ss += v[i].x * v[i].x + v[i].y * v[i].y + v[i].z * v[i].z + v[i].w * v[i].w;
        }
#pragma unroll
        for (int off = 32; off; off >>= 1) {
            s += __shfl_xor(s, off);
            ss += __shfl_xor(ss, off);
        }
        float m = s * (1.f / DIM);
        float rstd = rsqrtf(ss * (1.f / DIM) - m * m + 1e-5f);
#pragma unroll
        for (int i = 0; i < 4; i++) {
            int e = (lane + i * 64) * 4;
            float4 lw = *(const float4*)&lnw[e];
            float4 lb = *(const float4*)&lnb[e];
            ushort4 un, ur;
            un.x = f2b((v[i].x - m) * rstd * lw.x + lb.x);
            un.y = f2b((v[i].y - m) * rstd * lw.y + lb.y);
            un.z = f2b((v[i].z - m) * rstd * lw.z + lb.z);
            un.w = f2b((v[i].w - m) * rstd * lw.w + lb.w);
            ur.x = f2b(v[i].x); ur.y = f2b(v[i].y); ur.z = f2b(v[i].z); ur.w = f2b(v[i].w);
            *(ushort4*)&xnb[(size_t)row * DIM + e] = un;
            *(ushort4*)&xb[(size_t)row * DIM + e] = ur;
        }
    } else {
        // ---- weight transpose part ----
        const int i = blockIdx.x - 1024;
        const int z = i >> 8;
        const int k0 = ((i >> 4) & 15) * 64, n0 = (i & 15) * 64;
        const float* W = (z == 0) ? W0 : (z == 1) ? W1 : (z == 2) ? W2 : W3;
        unsigned short* T = (z == 0) ? T0 : (z == 1) ? T1 : (z == 2) ? T2 : T3;
        const int r = threadIdx.x >> 3;
        const int c = (threadIdx.x & 7) * 8;
#pragma unroll
        for (int half = 0; half < 2; half++) {
            int rr = r + half * 32;
            float4 a = *(const float4*)&W[(size_t)(k0 + rr) * DIM + n0 + c];
            float4 b = *(const float4*)&W[(size_t)(k0 + rr) * DIM + n0 + c + 4];
            tile[rr][c + 0] = a.x; tile[rr][c + 1] = a.y; tile[rr][c + 2] = a.z; tile[rr][c + 3] = a.w;
            tile[rr][c + 4] = b.x; tile[rr][c + 5] = b.y; tile[rr][c + 6] = b.z; tile[rr][c + 7] = b.w;
        }
        __syncthreads();
#pragma unroll
        for (int half = 0; half < 2; half++) {
            int dd = r + half * 32;
            bf16x8 o;
#pragma unroll
            for (int j = 0; j < 8; j++) o[j] = (short)f2b(tile[c + j][dd]);
            *(bf16x8*)&T[(size_t)(n0 + dd) * DIM + k0 + c] = o;
        }
    }
}

// ---------------------------------------------------------------------------
// Kernel 3: bf16 MFMA GEMM, BK=32, 4 waves (2x2), XCD swizzle.
// FINAL config (best-measured, R13 = 213.6us). Pipelining matrix fully
// explored across R6/R11/R12/R14: {1 vs 2 barriers} x {drain vs counted
// vmcnt} all statistically identical (~48us GEMM0) — 2-phase stage+wait+
// barrier overhead is structural (m233); keeping the R13-measured variant.
// MODE 0: tile 128x128, depth-2 counted-vmcnt (3 LDS buffers, vmcnt(8)).
//   z=0/1 (Q/K): fused l2norm + gate; z=2 (V): plain. z=0 (Q) output
//   pre-scaled by K1 = -SHARP*LOG2E (sigmoid fold); +K0 goes in the attn
//   MFMA C-operand. gq gate uses the UNSCALED normalized q.
// MODE 1: tile 128x64, C = collapse @ Wot^T + bias, 2-buf syncthreads.
// ---------------------------------------------------------------------------
template <int MODE>
__global__ __launch_bounds__(256) void gemm_mfma_kernel(
    const unsigned short* __restrict__ A0,
    const unsigned short* __restrict__ Bt0, const unsigned short* __restrict__ Bt1,
    const unsigned short* __restrict__ Bt2, const float* __restrict__ bias,
    const float* __restrict__ gq, const float* __restrict__ gk,
    unsigned short* __restrict__ Oq, unsigned short* __restrict__ Ok,
    unsigned short* __restrict__ Ov, float* __restrict__ gq_t, float* __restrict__ gk_t,
    float* __restrict__ Oout, const unsigned short* __restrict__ A2) {
    constexpr int NT = (MODE == 0) ? 4 : 2;    // n-frags per wave; block n-tile = NT*32
    constexpr int NBUF = (MODE == 0) ? 3 : 2;  // pipeline depth (MODE0 depth-2)
    __shared__ __align__(16) unsigned short As[NBUF][128 * 32];
    __shared__ __align__(16) unsigned short Bs[NBUF][NT * 32 * 32];
    const int tid = threadIdx.x;
    const int lane = tid & 63, w = tid >> 6;
    const int l16 = lane & 15, quad = lane >> 4;
    const int wm = w >> 1, wn = w & 1;
    int m0, n0, z = 0;
    if constexpr (MODE == 0) {
        // 768 blocks; w = z*256 + m*8 + n; XCD chunk = 96 consecutive w.
        const int f = blockIdx.x + (blockIdx.y << 5) + (blockIdx.z << 8);
        const int ww = (f & 7) * 96 + (f >> 3);
        z = ww >> 8;
        m0 = ((ww >> 3) & 31) * 128;
        n0 = (ww & 7) * 128;
    } else {
        // 512 blocks; w = m*16 + n; XCD chunk = 64 consecutive w (4m x 16n).
        const int f = blockIdx.x + (blockIdx.y << 5);
        const int ww = (f & 7) * 64 + (f >> 3);
        m0 = (ww >> 4) * 128;
        n0 = (ww & 15) * 64;
    }
    const unsigned short* A;
    const unsigned short* Bt;
    if constexpr (MODE == 0) {
        A = (z == 2) ? A2 : A0;
        Bt = (z == 0) ? Bt0 : (z == 1) ? Bt1 : Bt2;
    } else {
        A = A0;
        Bt = Bt0;
    }
    f32x4 acc[4][NT] = {};
    const int kswz = (l16 >> 1) & 3;

    // staging geometry (per thread, 2 instances)
    const int lin0 = tid, lin1 = 256 + tid;
    const int sm0 = lin0 >> 2, sk0 = (lin0 & 3) ^ ((sm0 >> 1) & 3);
    const int sm1 = lin1 >> 2, sk1 = (lin1 & 3) ^ ((sm1 >> 1) & 3);

    auto stage_async = [&](int kb, int k0) {
        async_cp16(Bt + (size_t)(n0 + sm0) * DIM + k0 + sk0 * 8, &Bs[kb][lin0 * 8]);
        if constexpr (MODE == 0)
            async_cp16(Bt + (size_t)(n0 + sm1) * DIM + k0 + sk1 * 8, &Bs[kb][lin1 * 8]);
        async_cp16(A + (size_t)(m0 + sm0) * DIM + k0 + sk0 * 8, &As[kb][lin0 * 8]);
        async_cp16(A + (size_t)(m0 + sm1) * DIM + k0 + sk1 * 8, &As[kb][lin1 * 8]);
    };

    auto compute = [&](int cur) {
        bf16x8 af[4], bfr[NT];
#pragma unroll
        for (int t = 0; t < 4; t++) {
            int ma = wm * 64 + t * 16 + l16;
            af[t] = *(const bf16x8*)(&As[cur][ma * 32 + ((quad ^ kswz) * 8)]);
        }
#pragma unroll
        for (int t = 0; t < NT; t++) {
            int nb = wn * (NT * 16) + t * 16 + l16;
            bfr[t] = *(const bf16x8*)(&Bs[cur][nb * 32 + ((quad ^ kswz) * 8)]);
        }
#pragma unroll
        for (int mt = 0; mt < 4; mt++)
#pragma unroll
            for (int nt = 0; nt < NT; nt++)
                acc[mt][nt] =
                    __builtin_amdgcn_mfma_f32_16x16x32_bf16(af[mt], bfr[nt], acc[mt][nt], 0, 0, 0);
    };

    if constexpr (MODE == 0) {
        // Depth-2 T4 pipeline (4 vmem ops per stage, nothing else in-loop).
        stage_async(0, 0);
        stage_async(1, 32);
        int cur = 0, stg = 2;
        for (int ks = 0; ks < DIM / 32; ks++) {
            __builtin_amdgcn_s_barrier();  // WAR: buf 'stg' readers (iter ks-1) done
            if (ks + 2 < DIM / 32) {
                stage_async(stg, (ks + 2) * 32);
                asm volatile("s_waitcnt vmcnt(8)" ::: "memory");  // tile ks landed
            } else if (ks + 1 < DIM / 32) {
                asm volatile("s_waitcnt vmcnt(4)" ::: "memory");  // tile ks landed
            } else {
                asm volatile("s_waitcnt vmcnt(0)" ::: "memory");  // final tile
            }
            __builtin_amdgcn_s_barrier();  // RAW: every wave's tile-ks loads landed
            compute(cur);
            cur = (cur == 2) ? 0 : cur + 1;
            stg = (stg == 2) ? 0 : stg + 1;
        }
    } else {
        stage_async(0, 0);
        __syncthreads();
        for (int ks = 0; ks < DIM / 32; ks++) {
            const int cur = ks & 1;
            if (ks + 1 < DIM / 32) stage_async(cur ^ 1, (ks + 1) * 32);
            compute(cur);
            __syncthreads();
        }
    }

    if constexpr (MODE == 0) {
        const int h = (n0 + wn * 64) >> 6;  // this wave's head
        if (z <= 1) {
            constexpr float QSCALE = -SHARP * LOG2E;  // fold sigmoid arg scale into Q
            const float* gvec = (z == 0) ? gq : gk;
            float* gate = (z == 0) ? gq_t : gk_t;
            unsigned short* O = (z == 0) ? Oq : Ok;
            const float oscale = (z == 0) ? QSCALE : 1.0f;
            float gv[4];
#pragma unroll
            for (int nt = 0; nt < 4; nt++) gv[nt] = gvec[nt * 16 + l16];
#pragma unroll
            for (int mt = 0; mt < 4; mt++) {
#pragma unroll
                for (int r = 0; r < 4; r++) {
                    float ss = 0.f;
#pragma unroll
                    for (int nt = 0; nt < 4; nt++) ss += acc[mt][nt][r] * acc[mt][nt][r];
#pragma unroll
                    for (int msk = 1; msk < 16; msk <<= 1) ss += __shfl_xor(ss, msk);
                    float rn = __builtin_amdgcn_rcpf(fmaxf(sqrtf(ss), 1e-12f));
                    float vn[4], gg = 0.f;
#pragma unroll
                    for (int nt = 0; nt < 4; nt++) {
                        vn[nt] = acc[mt][nt][r] * rn;
                        gg += vn[nt] * gv[nt];
                    }
#pragma unroll
                    for (int msk = 1; msk < 16; msk <<= 1) gg += __shfl_xor(gg, msk);
                    int tok = m0 + wm * 64 + mt * 16 + quad * 4 + r;
                    int b = tok >> 11, t = tok & 2047;
                    size_t rowbase = ((size_t)(b * HEADS + h) * T_SEQ + t) * HD;
#pragma unroll
                    for (int nt = 0; nt < 4; nt++)
                        O[rowbase + nt * 16 + l16] = f2b(vn[nt] * oscale);
                    if (l16 == 0) gate[(b * HEADS + h) * T_SEQ + t] = gg;
                }
            }
        } else {
#pragma unroll
            for (int mt = 0; mt < 4; mt++) {
#pragma unroll
                for (int r = 0; r < 4; r++) {
                    int tok = m0 + wm * 64 + mt * 16 + quad * 4 + r;
                    int b = tok >> 11, t = tok & 2047;
                    size_t rowbase = ((size_t)(b * HEADS + h) * T_SEQ + t) * HD;
#pragma unroll
                    for (int nt = 0; nt < 4; nt++)
                        Ov[rowbase + nt * 16 + l16] = f2b(acc[mt][nt][r]);
                }
            }
        }
    } else {
        float bias_r[NT];
#pragma unroll
        for (int nt = 0; nt < NT; nt++) bias_r[nt] = bias[n0 + wn * (NT * 16) + nt * 16 + l16];
#pragma unroll
        for (int mt = 0; mt < 4; mt++) {
#pragma unroll
            for (int r = 0; r < 4; r++) {
                int tok = m0 + wm * 64 + mt * 16 + quad * 4 + r;
#pragma unroll
                for (int nt = 0; nt < NT; nt++) {
                    int n = n0 + wn * (NT * 16) + nt * 16 + l16;
                    Oout[(size_t)tok * DIM + n] = acc[mt][nt][r] + bias_r[nt];
                }
            }
        }
    }
}

// ---------------------------------------------------------------------------
// Kernel 4: bf16 transpose V[bh][t][d] -> Vt[bh][d][t], fused gate_k scale.
// ---------------------------------------------------------------------------
__global__ __launch_bounds__(256) void vtrans_kernel(const unsigned short* __restrict__ Vn,
                                                     const float* __restrict__ gk_t,
                                                     unsigned short* __restrict__ Vt) {
    __shared__ float tile[64][65];
    const int bh = blockIdx.y;
    const int t0 = blockIdx.x * 64;
    const int r = threadIdx.x >> 3;
    const int c = (threadIdx.x & 7) * 8;
    const unsigned short* src = Vn + (size_t)bh * T_SEQ * HD;
#pragma unroll
    for (int half = 0; half < 2; half++) {
        int rr = r + half * 32;
        float gkv = gk_t[bh * T_SEQ + t0 + rr];
        bf16x8 v = *(const bf16x8*)(src + (size_t)(t0 + rr) * HD + c);
#pragma unroll
        for (int j = 0; j < 8; j++) tile[rr][c + j] = b2f((unsigned short)v[j]) * gkv;
    }
    __syncthreads();
    unsigned short* dst = Vt + (size_t)bh * HD * T_SEQ;
#pragma unroll
    for (int half = 0; half < 2; half++) {
        int dd = r + half * 32;
        bf16x8 o;
#pragma unroll
        for (int j = 0; j < 8; j++) o[j] = (short)f2b(tile[c + j][dd]);
        *(bf16x8*)(dst + (size_t)dd * T_SEQ + t0 + c) = o;
    }
}

// ---------------------------------------------------------------------------
// Kernel 5: MFMA gated attention (R13 FINAL: full s-range per block, 512
// blocks, single f32 accumulation, final gq-scaled bf16 collapse written
// directly — verified -8us net vs s-split partials).
// ---------------------------------------------------------------------------
__global__ __launch_bounds__(256, 4) void attn_mfma_kernel(
    const unsigned short* __restrict__ Qn, const unsigned short* __restrict__ Kn,
    const unsigned short* __restrict__ Vt, const float* __restrict__ gateq,
    unsigned short* __restrict__ coll) {
    __shared__ __align__(16) unsigned short Ks[2][64 * 64];   // [s][d], swizzled groups
    __shared__ __align__(16) unsigned short VtL[2][64 * 64];  // [d][s], swizzled groups
    const int tid = threadIdx.x;
    const int lane = tid & 63, w = tid >> 6;
    const int quad = lane >> 4, l16 = lane & 15;
    // XCD-clustering remap (bijective over 512 blocks; xcd = flat%8):
    // panel(b,h) = (f&7)*4 + ((f>>3)>>4); t-block = (f>>3)&15.
    const int f = blockIdx.x + 16 * blockIdx.y + 256 * blockIdx.z;
    const int q_ = f >> 3;
    const int panel = (f & 7) * 4 + (q_ >> 4);
    const int t0 = (q_ & 15) * 128;
    const int h = panel & 15;
    const int b = panel >> 4;
    const int bh = b * HEADS + h;
    const size_t base = (size_t)bh * T_SEQ * HD;  // == bh*HD*T_SEQ for Vt
    constexpr float K0 = THRESH * SHARP * LOG2E;  // sigmoid arg = sacc (K1 in Q)
    const f32x4 k0v = {K0, K0, K0, K0};

    // Detect v_permlane16_swap_b32 output order once (uniform).
    int det0 = quad, det1 = quad + 4;
    asm("v_permlane16_swap_b32 %0, %1" : "+v"(det0), "+v"(det1));
    const bool flagA = (__builtin_amdgcn_readfirstlane(det0) == 0);

    // Q (B-operand of QK) fragments: 32 rows/wave, 2 m-tiles, in regs.
    bf16x8 fq[2][2];
#pragma unroll
    for (int mt = 0; mt < 2; mt++) {
        const unsigned short* qrow = Qn + base + (size_t)(t0 + w * 32 + mt * 16 + l16) * HD;
        fq[mt][0] = *(const bf16x8*)(qrow + quad * 8);
        fq[mt][1] = *(const bf16x8*)(qrow + 32 + quad * 8);
    }

    f32x4 oacc[4][2] = {};  // [dt][mt], O^T C-layout
    const int srow = tid >> 3;     // staging row 0..31 (+32 second inst)
    const int sgp = tid & 7;       // physical 16B group
    const int swz = l16 & 7;

    auto stage_chunk = [&](unsigned short* ksn, unsigned short* vtn, int s0) {
#pragma unroll
        for (int half = 0; half < 2; half++) {
            int row = srow + half * 32;
            int g = sgp ^ (row & 7);  // logical group for this physical slot
            async_cp16(Kn + base + (size_t)(s0 + row) * HD + g * 8, ksn + row * 64 + sgp * 8);
            async_cp16(Vt + base + (size_t)row * T_SEQ + s0 + g * 8, vtn + row * 64 + sgp * 8);
        }
    };

    auto do_chunk = [&](const unsigned short* ksb, const unsigned short* vtb) {
#pragma unroll
        for (int kh = 0; kh < 2; kh++) {
            // ---- QK for this kh's s-range (2 ct tiles); sigmoid; bf16 S in regs ----
            unsigned int p[2][2][2];  // [mt][ct2][dword]
#pragma unroll
            for (int ct2 = 0; ct2 < 2; ct2++) {
                const int ct = 2 * kh + ct2;
                const unsigned short* krow = ksb + (ct * 16 + l16) * 64;
                bf16x8 fk0 = *(const bf16x8*)(krow + (quad ^ swz) * 8);
                bf16x8 fk1 = *(const bf16x8*)(krow + ((quad + 4) ^ swz) * 8);
#pragma unroll
                for (int mt = 0; mt < 2; mt++) {
                    __builtin_amdgcn_s_setprio(1);
                    f32x4 s1 =
                        __builtin_amdgcn_mfma_f32_16x16x32_bf16(fk0, fq[mt][0], k0v, 0, 0, 0);
                    f32x4 sacc =
                        __builtin_amdgcn_mfma_f32_16x16x32_bf16(fk1, fq[mt][1], s1, 0, 0, 0);
                    __builtin_amdgcn_s_setprio(0);
                    float w0 = __builtin_amdgcn_rcpf(1.f + __builtin_amdgcn_exp2f(sacc[0]));
                    float w1 = __builtin_amdgcn_rcpf(1.f + __builtin_amdgcn_exp2f(sacc[1]));
                    float w2 = __builtin_amdgcn_rcpf(1.f + __builtin_amdgcn_exp2f(sacc[2]));
                    float w3 = __builtin_amdgcn_rcpf(1.f + __builtin_amdgcn_exp2f(sacc[3]));
                    p[mt][ct2][0] = pack2_bf16(w0, w1);
                    p[mt][ct2][1] = pack2_bf16(w2, w3);
                }
            }
            // ---- SV for this kh: O^T += V^T S^T, B-frag via permlane16_swap ----
            int gv = (4 * kh + 2 * (quad & 1) + (quad >> 1)) ^ swz;
            bf16x8 fv[4];
#pragma unroll
            for (int dt = 0; dt < 4; dt++)
                fv[dt] = *(const bf16x8*)(vtb + (dt * 16 + l16) * 64 + gv * 8);
#pragma unroll
            for (int mt = 0; mt < 2; mt++) {
                unsigned int aL = p[mt][0][0], aH = p[mt][0][1];
                unsigned int bL = p[mt][1][0], bH = p[mt][1][1];
                asm("v_permlane16_swap_b32 %0, %1" : "+v"(aL), "+v"(bL));
                asm("v_permlane16_swap_b32 %0, %1" : "+v"(aH), "+v"(bH));
                u32x4 bt;
                if (flagA) {  // wave-uniform branch, no per-lane selects
                    bt.x = aL; bt.y = aH; bt.z = bL; bt.w = bH;
                } else {
                    bt.x = bL; bt.y = bH; bt.z = aL; bt.w = aH;
                }
                bf16x8 fs = __builtin_bit_cast(bf16x8, bt);
                __builtin_amdgcn_s_setprio(1);
#pragma unroll
                for (int dt = 0; dt < 4; dt++)
                    oacc[dt][mt] =
                        __builtin_amdgcn_mfma_f32_16x16x32_bf16(fv[dt], fs, oacc[dt][mt], 0, 0, 0);
                __builtin_amdgcn_s_setprio(0);
            }
        }
        __syncthreads();
    };

    stage_chunk(&Ks[0][0], &VtL[0][0], 0);
    __syncthreads();

    for (int j = 0; j < T_SEQ / 128; j++) {
        // even chunk (buf 0): prefetch odd chunk into buf 1 (always in range)
        stage_chunk(&Ks[1][0], &VtL[1][0], j * 128 + 64);
        do_chunk(&Ks[0][0], &VtL[0][0]);
        // odd chunk (buf 1): prefetch next even chunk into buf 0
        if (j + 1 < T_SEQ / 128) stage_chunk(&Ks[0][0], &VtL[0][0], j * 128 + 128);
        do_chunk(&Ks[1][0], &VtL[1][0]);
    }

    // ---- epilogue: O^T lanes hold 4 consecutive d; * gate_q, b64 writes ----
#pragma unroll
    for (int mt = 0; mt < 2; mt++) {
        int t = t0 + w * 32 + mt * 16 + l16;
        float gq_v = gateq[bh * T_SEQ + t];
        unsigned short* dst = coll + ((size_t)b * T_SEQ + t) * DIM + h * HD;
#pragma unroll
        for (int dt = 0; dt < 4; dt++) {
            ushort4 o;
            o.x = f2b(oacc[dt][mt][0] * gq_v);
            o.y = f2b(oacc[dt][mt][1] * gq_v);
            o.z = f2b(oacc[dt][mt][2] * gq_v);
            o.w = f2b(oacc[dt][mt][3] * gq_v);
            *(ushort4*)(dst + dt * 16 + quad * 4) = o;
        }
    }
}

// ---------------------------------------------------------------------------
extern "C" void kernel_launch(void* const* d_in, const int* in_sizes, int n_in,
                              void* d_out, int out_size, void* d_ws, size_t ws_size,
                              hipStream_t stream) {
    const float* x = (const float*)d_in[0];
    const float* Wq = (const float*)d_in[1];
    const float* Wk = (const float*)d_in[2];
    const float* Wv = (const float*)d_in[3];
    const float* gq = (const float*)d_in[4];
    const float* gk = (const float*)d_in[5];
    const float* Wo = (const float*)d_in[6];
    const float* bo = (const float*)d_in[7];
    const float* lnw = (const float*)d_in[8];
    const float* lnb = (const float*)d_in[9];
    float* out = (float*)d_out;

    // Workspace ~59.3 MB. Aliases safe by stream ordering: Vt overwrites xnb
    // (dead after QKV GEMM); coll overwrites xb (dead after QKV GEMM).
    unsigned short* ws = (unsigned short*)d_ws;
    unsigned short* xnb = ws;                           // bf16 [4096][1024]
    unsigned short* xb = xnb + (size_t)NTOK * DIM;      // bf16 [4096][1024]
    unsigned short* Wqt = xb + (size_t)NTOK * DIM;      // bf16 [1024][1024] (W^T)
    unsigned short* Wkt = Wqt + (size_t)DIM * DIM;
    unsigned short* Wvt = Wkt + (size_t)DIM * DIM;
    unsigned short* Wot = Wvt + (size_t)DIM * DIM;
    unsigned short* Q16 = Wot + (size_t)DIM * DIM;      // bf16 [B,H,T,hd] (normalized * K1)
    unsigned short* K16 = Q16 + (size_t)NTOK * DIM;     // bf16 (normalized)
    unsigned short* Vn = K16 + (size_t)NTOK * DIM;      // bf16 [B,H,T,hd]
    float* gq_t = (float*)(Vn + (size_t)NTOK * DIM);    // [B,H,T]
    float* gk_t = gq_t + NBATCH * HEADS * T_SEQ;
    unsigned short* Vt = xnb;   // alias: bf16 [B,H,hd,T], gk-scaled
    unsigned short* coll = xb;  // alias: bf16 final collapse [B,T,D]

    prep_kernel<<<2048, 256, 0, stream>>>(x, lnw, lnb, xnb, xb, Wq, Wk, Wv, Wo, Wqt, Wkt, Wvt,
                                          Wot);
    gemm_mfma_kernel<0><<<dim3(NTOK / 128, DIM / 128, 3), 256, 0, stream>>>(
        xnb, Wqt, Wkt, Wvt, nullptr, gq, gk, Q16, K16, Vn, gq_t, gk_t, nullptr, xb);
    vtrans_kernel<<<dim3(T_SEQ / 64, NBATCH * HEADS), 256, 0, stream>>>(Vn, gk_t, Vt);
    attn_mfma_kernel<<<dim3(16, 16, 2), 256, 0, stream>>>(Q16, K16, Vt, gq_t, coll);
    gemm_mfma_kernel<1><<<dim3(NTOK / 128, DIM / 64, 1), 256, 0, stream>>>(
        coll, Wot, nullptr, nullptr, bo, nullptr, nullptr, nullptr, nullptr, nullptr, nullptr,
        nullptr, out, nullptr);
}